// Round 3
// baseline (470.435 us; speedup 1.0000x reference)
//
#include <hip/hip_runtime.h>

#define Bsz 4096
#define Tt  256
#define Ff  32
#define H1  64
#define H2  32
#define NTAPS 3
#define BT  8       // batch tile: 512 blocks -> 2 co-resident blocks/CU
#define NTHR 384    // 6 waves: 4 L1 bundles + 2 L2 bundles

typedef _Float16 half8  __attribute__((ext_vector_type(8)));
typedef _Float16 half2v __attribute__((ext_vector_type(2)));
typedef float    f32x4  __attribute__((ext_vector_type(4)));

#define H1S 72   // f16 row stride (16B-aligned rows)
#define XS  40
#define H2S 40
#define HDS 33

// fused LSTM unit: 5 exp + 3 rcp (was 5 exp + 5 rcp)
__device__ __forceinline__ float lstm_unit(float pi, float pf, float pg, float po,
                                           float& c) {
    const float K1 = 1.4426950408889634f;   // log2(e)
    float ei = __builtin_amdgcn_exp2f(-K1 * pi);
    float ef = __builtin_amdgcn_exp2f(-K1 * pf);
    float eg = __builtin_amdgcn_exp2f(-2.0f * K1 * __builtin_fabsf(pg));
    float eo = __builtin_amdgcn_exp2f(-K1 * po);
    float f_ = __builtin_amdgcn_rcpf(1.0f + ef);
    // i*g = sigmoid(pi)*tanh(pg) = sign(pg)*(1-eg)*rcp((1+ei)*(1+eg))
    float ig = (1.0f - eg) * __builtin_amdgcn_rcpf((1.0f + ei) * (1.0f + eg));
    ig = __builtin_copysignf(ig, pg);
    c = f_ * c + ig;
    // h = sigmoid(po)*tanh(c) = sign(c)*(1-ec)*rcp((1+eo)*(1+ec))
    float ec = __builtin_amdgcn_exp2f(-2.0f * K1 * __builtin_fabsf(c));
    float th = (1.0f - ec) * __builtin_amdgcn_rcpf((1.0f + eo) * (1.0f + ec));
    return __builtin_copysignf(th, c);
}

#define MFMA16(a, b, c) __builtin_amdgcn_mfma_f32_16x16x32_f16((a), (b), (c), 0, 0, 0)

__global__ __launch_bounds__(NTHR, 3)
void lstm2_fused(const float* __restrict__ x,
                 const float* __restrict__ Wih1, const float* __restrict__ Whh1,
                 const float* __restrict__ bih1, const float* __restrict__ bhh1,
                 const float* __restrict__ Wih2, const float* __restrict__ Whh2,
                 const float* __restrict__ bih2, const float* __restrict__ bhh2,
                 const float* __restrict__ Whead, const float* __restrict__ bhead,
                 float* __restrict__ out)
{
    // h1(t) in sH1[t&1]; h2(t) in sH2[t&1]; x(t) in sX[t&1]; 8 batch rows each
    __shared__ __align__(16) _Float16 sH1[2][BT][H1S];
    __shared__ __align__(16) _Float16 sX [2][BT][XS];
    __shared__ __align__(16) _Float16 sH2[2][BT][H2S];
    __shared__ __align__(16) float    sHead[BT][HDS];

    const int tid  = threadIdx.x;
    const int wid  = tid >> 6;        // 0..5
    const int lane = tid & 63;
    const int l15  = lane & 15;
    const int q    = lane >> 4;       // 0..3
    const int row8 = l15 & 7;         // A-frag row: rows 8..15 duplicate 0..7
    const int b0   = blockIdx.x * BT;

    const bool isL1 = (wid < 4);
    const int  hg   = isL1 ? wid : (wid - 4);   // L1: 0..3, L2: 0..1

    // activation unit mapping (duplicate-row trick):
    //  q=0: regs{0,1}=b{0,1}  q=1: regs{0,1}=b{4,5}  q=2: regs{2,3}=b{2,3}  q=3: regs{2,3}=b{6,7}
    const int r0  = (q >> 1) * 2, r1 = r0 + 1;
    const int bLo = (q & 1) * 4 + (q >> 1) * 2;
    const int col = hg * 16 + l15;              // h index within this wave's layer

    // ---- per-wave weight fragments (registers, one time) ----
    half8 w[4][3];
    float bias[4];
    if (isL1) {
        #pragma unroll
        for (int G = 0; G < 4; ++G) {
            int gr = G * 64 + hg * 16 + l15;
            #pragma unroll
            for (int c = 0; c < 3; ++c) {
                half8 v;
                #pragma unroll
                for (int e = 0; e < 8; ++e) {
                    int k = c * 32 + q * 8 + e;                 // 0..63: h1(t-1), 64..95: x(t)
                    float f = (k < H1) ? Whh1[gr * H1 + k] : Wih1[gr * Ff + (k - H1)];
                    v[e] = (_Float16)f;
                }
                w[G][c] = v;
            }
            bias[G] = bih1[gr] + bhh1[gr];
        }
    } else {
        #pragma unroll
        for (int G = 0; G < 4; ++G) {
            int gr = G * 32 + hg * 16 + l15;
            #pragma unroll
            for (int c = 0; c < 3; ++c) {
                half8 v;
                #pragma unroll
                for (int e = 0; e < 8; ++e) {
                    int kk = q * 8 + e;                         // c0: h2(t-1), c1/c2: h1(t)
                    float f = (c == 0) ? Whh2[gr * H2 + kk]
                                       : Wih2[gr * H1 + (c - 1) * 32 + kk];
                    v[e] = (_Float16)f;
                }
                w[G][c] = v;
            }
            bias[G] = bih2[gr] + bhh2[gr];
        }
    }

    // ---- zero h(-1) buffers ----
    for (int idx = tid; idx < BT * H1S; idx += NTHR) ((_Float16*)sH1[1])[idx] = (_Float16)0.0f;
    for (int idx = tid; idx < BT * H2S; idx += NTHR) ((_Float16*)sH2[1])[idx] = (_Float16)0.0f;

    // ---- x prologue (L2 waves, 128 threads): x(0)->sX[0]; prefetch x(1),x(2) ----
    float2 rA, rB;
    int xb = 0, xf = 0;
    if (tid >= 256) {
        int t = tid - 256;                 // 0..127
        xb = t >> 4; xf = (t & 15) * 2;    // 8 rows x 32 cols
        const float* xp = x + ((size_t)(b0 + xb) * Tt) * Ff + xf;
        float2 v0 = *(const float2*)xp;
        half2v h0; h0[0] = (_Float16)v0.x; h0[1] = (_Float16)v0.y;
        *(half2v*)&sX[0][xb][xf] = h0;
        rA = *(const float2*)(xp + 1 * Ff);
        rB = *(const float2*)(xp + 2 * Ff);
    }
    __syncthreads();

    float cs0 = 0.0f, cs1 = 0.0f;   // cell state for this lane's 2 units

    for (int i = 0; i <= Tt; ++i) {
        const int cur = i & 1, nxt = cur ^ 1;
        const bool active = isL1 ? (i < Tt) : (i >= 1);

        if (active) {
            half8 a0 = *(const half8*)&sH1[nxt][row8][q * 8];        // h1(i-1) k 0..31
            half8 a1 = *(const half8*)&sH1[nxt][row8][32 + q * 8];   // h1(i-1) k 32..63
            half8 A0, A1, A2;
            if (isL1) {
                half8 ax = *(const half8*)&sX[cur][row8][q * 8];     // x(i)
                A0 = a0; A1 = a1; A2 = ax;
            } else {
                half8 ah = *(const half8*)&sH2[cur][row8][q * 8];    // h2(i-2)
                A0 = ah; A1 = a0; A2 = a1;
            }
            f32x4 acc[4];
            #pragma unroll
            for (int G = 0; G < 4; ++G) {
                f32x4 a = {bias[G], bias[G], bias[G], bias[G]};
                a = MFMA16(A0, w[G][0], a);
                a = MFMA16(A1, w[G][1], a);
                a = MFMA16(A2, w[G][2], a);
                acc[G] = a;
            }

            float h0 = lstm_unit(acc[0][r0], acc[1][r0], acc[2][r0], acc[3][r0], cs0);
            float h1v = lstm_unit(acc[0][r1], acc[1][r1], acc[2][r1], acc[3][r1], cs1);

            if (isL1) {
                sH1[cur][bLo][col]     = (_Float16)h0;    // h1(i)
                sH1[cur][bLo + 1][col] = (_Float16)h1v;
            } else {
                sH2[nxt][bLo][col]     = (_Float16)h0;    // h2(i-1)
                sH2[nxt][bLo + 1][col] = (_Float16)h1v;
                if (i == Tt) { sHead[bLo][col] = h0; sHead[bLo + 1][col] = h1v; }
            }
        }

        // x duty (L2 waves): stage x(i+1), prefetch x(i+3)
        if (tid >= 256) {
            if (i + 1 < Tt) {
                half2v hx; hx[0] = (_Float16)rA.x; hx[1] = (_Float16)rA.y;
                *(half2v*)&sX[nxt][xb][xf] = hx;
            }
            rA = rB;
            int tld = (i + 3 < Tt) ? (i + 3) : (Tt - 1);
            rB = *(const float2*)(x + ((size_t)(b0 + xb) * Tt + tld) * Ff + xf);
        }
        __syncthreads();   // single barrier per step
    }

    // ---- head: out[b,n] = b_head[n] + sum_k h2_last[b,k] * W_head[n,k] ----
    if (tid < BT * NTAPS) {
        int b = tid / NTAPS, n = tid - b * NTAPS;
        float s = bhead[n];
        #pragma unroll
        for (int k = 0; k < H2; ++k) s = fmaf(sHead[b][k], Whead[n * H2 + k], s);
        out[(size_t)(b0 + b) * NTAPS + n] = s;
    }
}

extern "C" void kernel_launch(void* const* d_in, const int* in_sizes, int n_in,
                              void* d_out, int out_size, void* d_ws, size_t ws_size,
                              hipStream_t stream) {
    const float* xp    = (const float*)d_in[0];
    const float* Wih1  = (const float*)d_in[1];
    const float* Whh1  = (const float*)d_in[2];
    const float* bih1  = (const float*)d_in[3];
    const float* bhh1  = (const float*)d_in[4];
    const float* Wih2  = (const float*)d_in[5];
    const float* Whh2  = (const float*)d_in[6];
    const float* bih2  = (const float*)d_in[7];
    const float* bhh2  = (const float*)d_in[8];
    const float* Whead = (const float*)d_in[9];
    const float* bhead = (const float*)d_in[10];
    float* outp = (float*)d_out;

    hipLaunchKernelGGL(lstm2_fused, dim3(Bsz / BT), dim3(NTHR), 0, stream,
                       xp, Wih1, Whh1, bih1, bhh1, Wih2, Whh2, bih2, bhh2,
                       Whead, bhead, outp);
}

// Round 4
// 443.735 us; speedup vs baseline: 1.0602x; 1.0602x over previous
//
#include <hip/hip_runtime.h>

#define Bsz 4096
#define Tt  256
#define Ff  32
#define H1  64
#define H2  32
#define NTAPS 3
#define BT  8       // 512 blocks -> 2 co-resident blocks/CU, 1 wave/SIMD each
#define NTHR 256    // 4 UNIFORM waves; each does L1(i) + duplicated L2(i-1)

typedef _Float16 half8  __attribute__((ext_vector_type(8)));
typedef float    f32x4  __attribute__((ext_vector_type(4)));

#define H1S 72   // f16 row strides (16B-aligned, bank-spread)
#define XS  40
#define H2S 40
#define HDS 33

// fused LSTM unit: 5 exp + 3 rcp
__device__ __forceinline__ float lstm_unit(float pi, float pf, float pg, float po,
                                           float& c) {
    const float K1 = 1.4426950408889634f;   // log2(e)
    float ei = __builtin_amdgcn_exp2f(-K1 * pi);
    float ef = __builtin_amdgcn_exp2f(-K1 * pf);
    float eg = __builtin_amdgcn_exp2f(-2.0f * K1 * __builtin_fabsf(pg));
    float eo = __builtin_amdgcn_exp2f(-K1 * po);
    float f_ = __builtin_amdgcn_rcpf(1.0f + ef);
    float ig = (1.0f - eg) * __builtin_amdgcn_rcpf((1.0f + ei) * (1.0f + eg));
    ig = __builtin_copysignf(ig, pg);
    c = f_ * c + ig;
    float ec = __builtin_amdgcn_exp2f(-2.0f * K1 * __builtin_fabsf(c));
    float th = (1.0f - ec) * __builtin_amdgcn_rcpf((1.0f + eo) * (1.0f + ec));
    return __builtin_copysignf(th, c);
}

#define MFMA16(a, b, c) __builtin_amdgcn_mfma_f32_16x16x32_f16((a), (b), (c), 0, 0, 0)

__global__ __launch_bounds__(NTHR, 2)
void lstm2_fused(const float* __restrict__ x,
                 const float* __restrict__ Wih1, const float* __restrict__ Whh1,
                 const float* __restrict__ bih1, const float* __restrict__ bhh1,
                 const float* __restrict__ Wih2, const float* __restrict__ Whh2,
                 const float* __restrict__ bih2, const float* __restrict__ bhh2,
                 const float* __restrict__ Whead, const float* __restrict__ bhead,
                 float* __restrict__ out)
{
    __shared__ __align__(16) _Float16 sH1[2][BT][H1S];
    __shared__ __align__(16) _Float16 sX [2][BT][XS];
    __shared__ __align__(16) _Float16 sH2[2][BT][H2S];
    __shared__ __align__(16) float    sHead[BT][HDS];

    const int tid  = threadIdx.x;
    const int wid  = tid >> 6;        // 0..3 (uniform waves)
    const int lane = tid & 63;
    const int l15  = lane & 15;
    const int q    = lane >> 4;       // 0..3
    const int row8 = l15 & 7;         // A-frag rows duplicate with period 8
    const int b0   = blockIdx.x * BT;

    // L1: wave owns h-tile `wid` (h in [16*wid, 16*wid+16))
    const int colL1 = wid * 16 + l15;
    const int r0  = (q >> 1) * 2, r1 = r0 + 1;          // acc regs for 2 L1 units
    const int bLo = (q & 1) * 4 + (q >> 1) * 2;         // batches {bLo, bLo+1}
    // L2: wave-pair {2hT, 2hT+1} duplicates h-tile hT; wpar splits batches
    const int hT   = wid >> 1, wpar = wid & 1;
    const int hL2  = hT * 16 + l15;
    const int rL2  = 2 * wpar + (q >> 1);               // acc reg for the 1 L2 unit
    const int bL2  = (q & 1) * 4 + 2 * wpar + (q >> 1); // its batch

    // ---- weight fragments (registers, one time) ----
    half8 w1[4][3], w2[4][3];
    float bias1[4], bias2[4];
    #pragma unroll
    for (int G = 0; G < 4; ++G) {
        int gr1 = G * 64 + wid * 16 + l15;   // L1 gate row
        int gr2 = G * 32 + hT * 16 + l15;    // L2 gate row
        #pragma unroll
        for (int c = 0; c < 3; ++c) {
            half8 v1, v2;
            #pragma unroll
            for (int e = 0; e < 8; ++e) {
                int k = c * 32 + q * 8 + e;           // L1 K: 0..63 h1(t-1), 64..95 x(t)
                float f1 = (k < H1) ? Whh1[gr1 * H1 + k] : Wih1[gr1 * Ff + (k - H1)];
                int kk = q * 8 + e;                   // L2 K: c0 h2(t-1), c1/c2 h1(t)
                float f2 = (c == 0) ? Whh2[gr2 * H2 + kk]
                                    : Wih2[gr2 * H1 + (c - 1) * 32 + kk];
                v1[e] = (_Float16)f1; v2[e] = (_Float16)f2;
            }
            w1[G][c] = v1; w2[G][c] = v2;
        }
        bias1[G] = bih1[gr1] + bhh1[gr1];
        bias2[G] = bih2[gr2] + bhh2[gr2];
    }

    // ---- zero h(-1) buffers ----
    for (int idx = tid; idx < BT * H1S; idx += NTHR) ((_Float16*)sH1[1])[idx] = (_Float16)0.0f;
    for (int idx = tid; idx < BT * H2S; idx += NTHR) ((_Float16*)sH2[1])[idx] = (_Float16)0.0f;

    // ---- x prologue: 1 float/thread/step (8 rows x 32 cols = 256) ----
    const int xb = tid >> 5, xf = tid & 31;
    float rA, rB;
    {
        const float* xp = x + ((size_t)(b0 + xb) * Tt) * Ff + xf;
        sX[0][xb][xf] = (_Float16)xp[0];
        rA = xp[1 * Ff];
        rB = xp[2 * Ff];
    }
    __syncthreads();

    float cs0 = 0.0f, cs1 = 0.0f, cs2 = 0.0f;

    for (int i = 0; i <= Tt; ++i) {
        const int cur = i & 1, nxt = cur ^ 1;

        // h1(i-1) fragments (used by both L1(i) and L2(i-1))
        half8 a0 = *(const half8*)&sH1[nxt][row8][q * 8];
        half8 a1 = *(const half8*)&sH1[nxt][row8][32 + q * 8];

        if (i < Tt) {   // ---- L1 step i ----
            half8 ax = *(const half8*)&sX[cur][row8][q * 8];
            f32x4 acc[4];
            #pragma unroll
            for (int G = 0; G < 4; ++G) {
                f32x4 a = {bias1[G], bias1[G], bias1[G], bias1[G]};
                a = MFMA16(a0, w1[G][0], a);
                a = MFMA16(a1, w1[G][1], a);
                a = MFMA16(ax, w1[G][2], a);
                acc[G] = a;
            }
            float h0  = lstm_unit(acc[0][r0], acc[1][r0], acc[2][r0], acc[3][r0], cs0);
            float h1v = lstm_unit(acc[0][r1], acc[1][r1], acc[2][r1], acc[3][r1], cs1);
            sH1[cur][bLo][colL1]     = (_Float16)h0;
            sH1[cur][bLo + 1][colL1] = (_Float16)h1v;
        }
        if (i >= 1) {   // ---- L2 step i-1 (duplicated across wave pair) ----
            half8 ah = *(const half8*)&sH2[cur][row8][q * 8];
            f32x4 acc[4];
            #pragma unroll
            for (int G = 0; G < 4; ++G) {
                f32x4 a = {bias2[G], bias2[G], bias2[G], bias2[G]};
                a = MFMA16(ah, w2[G][0], a);
                a = MFMA16(a0, w2[G][1], a);
                a = MFMA16(a1, w2[G][2], a);
                acc[G] = a;
            }
            float h2v = lstm_unit(acc[0][rL2], acc[1][rL2], acc[2][rL2], acc[3][rL2], cs2);
            sH2[nxt][bL2][hL2] = (_Float16)h2v;
            if (i == Tt) sHead[bL2][hL2] = h2v;
        }

        // ---- x duty: stage x(i+1), prefetch x(i+3) ----
        if (i + 1 < Tt) sX[nxt][xb][xf] = (_Float16)rA;
        rA = rB;
        {
            int tld = (i + 3 < Tt) ? (i + 3) : (Tt - 1);
            rB = x[((size_t)(b0 + xb) * Tt + tld) * Ff + xf];
        }
        __syncthreads();   // single barrier per step
    }

    // ---- head ----
    if (tid < BT * NTAPS) {
        int b = tid / NTAPS, n = tid - b * NTAPS;
        float s = bhead[n];
        #pragma unroll
        for (int k = 0; k < H2; ++k) s = fmaf(sHead[b][k], Whead[n * H2 + k], s);
        out[(size_t)(b0 + b) * NTAPS + n] = s;
    }
}

extern "C" void kernel_launch(void* const* d_in, const int* in_sizes, int n_in,
                              void* d_out, int out_size, void* d_ws, size_t ws_size,
                              hipStream_t stream) {
    const float* xp    = (const float*)d_in[0];
    const float* Wih1  = (const float*)d_in[1];
    const float* Whh1  = (const float*)d_in[2];
    const float* bih1  = (const float*)d_in[3];
    const float* bhh1  = (const float*)d_in[4];
    const float* Wih2  = (const float*)d_in[5];
    const float* Whh2  = (const float*)d_in[6];
    const float* bih2  = (const float*)d_in[7];
    const float* bhh2  = (const float*)d_in[8];
    const float* Whead = (const float*)d_in[9];
    const float* bhead = (const float*)d_in[10];
    float* outp = (float*)d_out;

    hipLaunchKernelGGL(lstm2_fused, dim3(Bsz / BT), dim3(NTHR), 0, stream,
                       xp, Wih1, Whh1, bih1, bhh1, Wih2, Whh2, bih2, bhh2,
                       Whead, bhead, outp);
}

// Round 6
// 415.951 us; speedup vs baseline: 1.1310x; 1.0668x over previous
//
#include <hip/hip_runtime.h>

#define Bsz 4096
#define Tt  256
#define Ff  32
#define H1  64
#define H2  32
#define NTAPS 3
#define BT  8       // 512 blocks -> 2 co-resident blocks/CU, 1 wave/SIMD each
#define NTHR 256    // 4 UNIFORM waves
#define CH  16      // x-staging chunk (timesteps)

typedef _Float16 half8  __attribute__((ext_vector_type(8)));
typedef __fp16   fp16x2 __attribute__((ext_vector_type(2)));   // cvt_pkrtz return type
typedef float    f32x4  __attribute__((ext_vector_type(4)));

#define H1S 72   // f16 row strides (16B-aligned, bank-spread)
#define H2S 40
#define HDS 33

// fused LSTM unit: 5 exp + 3 rcp
__device__ __forceinline__ float lstm_unit(float pi, float pf, float pg, float po,
                                           float& c) {
    const float K1 = 1.4426950408889634f;   // log2(e)
    float ei = __builtin_amdgcn_exp2f(-K1 * pi);
    float ef = __builtin_amdgcn_exp2f(-K1 * pf);
    float eg = __builtin_amdgcn_exp2f(-2.0f * K1 * __builtin_fabsf(pg));
    float eo = __builtin_amdgcn_exp2f(-K1 * po);
    float f_ = __builtin_amdgcn_rcpf(1.0f + ef);
    float ig = (1.0f - eg) * __builtin_amdgcn_rcpf((1.0f + ei) * (1.0f + eg));
    ig = __builtin_copysignf(ig, pg);
    c = f_ * c + ig;
    float ec = __builtin_amdgcn_exp2f(-2.0f * K1 * __builtin_fabsf(c));
    float th = (1.0f - ec) * __builtin_amdgcn_rcpf((1.0f + eo) * (1.0f + ec));
    return __builtin_copysignf(th, c);
}

#define MFMA16(a, b, c) __builtin_amdgcn_mfma_f32_16x16x32_f16((a), (b), (c), 0, 0, 0)

// async global->LDS DMA, 16B per lane; LDS dst = uniform base + lane*16
__device__ __forceinline__ void dma16(const float* gp, const float* lp) {
    __builtin_amdgcn_global_load_lds(
        (const __attribute__((address_space(1))) void*)gp,
        (__attribute__((address_space(3))) void*)lp, 16, 0, 0);
}

__global__ __launch_bounds__(NTHR, 2)
void lstm2_fused(const float* __restrict__ x,
                 const float* __restrict__ Wih1, const float* __restrict__ Whh1,
                 const float* __restrict__ bih1, const float* __restrict__ bhh1,
                 const float* __restrict__ Wih2, const float* __restrict__ Whh2,
                 const float* __restrict__ bih2, const float* __restrict__ bhh2,
                 const float* __restrict__ Whead, const float* __restrict__ bhead,
                 float* __restrict__ out)
{
    __shared__ __align__(16) _Float16 sH1[2][BT][H1S];
    __shared__ __align__(16) _Float16 sH2[2][BT][H2S];
    // x chunk: [buf][t][f4][b][4] f32 — (f4-major, b-minor) so DMA lane*16B is contiguous
    __shared__ __align__(16) float    sXC[2][CH][8][8][4];
    __shared__ __align__(16) float    sHead[BT][HDS];

    const int tid  = threadIdx.x;
    const int wid  = tid >> 6;        // 0..3 (uniform waves)
    const int lane = tid & 63;
    const int l15  = lane & 15;
    const int q    = lane >> 4;       // 0..3
    const int row8 = l15 & 7;         // A-frag rows duplicate with period 8
    const int b0   = blockIdx.x * BT;

    // L1: wave owns h-tile `wid`
    const int colL1 = wid * 16 + l15;
    const int r0  = (q >> 1) * 2, r1 = r0 + 1;
    const int bLo = (q & 1) * 4 + (q >> 1) * 2;
    // L2: wave-pair duplicates h-tile hT; wpar splits batches
    const int hT   = wid >> 1, wpar = wid & 1;
    const int hL2  = hT * 16 + l15;
    const int rL2  = 2 * wpar + (q >> 1);
    const int bL2  = (q & 1) * 4 + 2 * wpar + (q >> 1);

    // per-lane DMA source base: batch bL, float-quad f4L
    const int bL  = lane & 7;
    const int f4L = lane >> 3;
    const float* gbase = x + (size_t)(b0 + bL) * Tt * Ff + f4L * 4;

    // ---- prologue: kick chunk 0 DMA immediately ----
    #pragma unroll
    for (int j = 0; j < 4; ++j) {
        int t = (wid << 2) | j;
        dma16(gbase + (size_t)t * Ff, &sXC[0][t][0][0][0]);
    }

    // ---- weight fragments (registers, one time) ----
    half8 w1[4][3], w2[4][3];
    float bias1[4], bias2[4];
    #pragma unroll
    for (int G = 0; G < 4; ++G) {
        int gr1 = G * 64 + wid * 16 + l15;   // L1 gate row
        int gr2 = G * 32 + hT * 16 + l15;    // L2 gate row
        #pragma unroll
        for (int c = 0; c < 3; ++c) {
            half8 v1, v2;
            #pragma unroll
            for (int e = 0; e < 8; ++e) {
                int k = c * 32 + q * 8 + e;           // L1 K: 0..63 h1(t-1), 64..95 x(t)
                float f1 = (k < H1) ? Whh1[gr1 * H1 + k] : Wih1[gr1 * Ff + (k - H1)];
                int kk = q * 8 + e;                   // L2 K: c0 h2(t-1), c1/c2 h1(t)
                float f2 = (c == 0) ? Whh2[gr2 * H2 + kk]
                                    : Wih2[gr2 * H1 + (c - 1) * 32 + kk];
                v1[e] = (_Float16)f1; v2[e] = (_Float16)f2;
            }
            w1[G][c] = v1; w2[G][c] = v2;
        }
        bias1[G] = bih1[gr1] + bhh1[gr1];
        bias2[G] = bih2[gr2] + bhh2[gr2];
    }

    // ---- zero h(-1) buffers ----
    for (int idx = tid; idx < BT * H1S; idx += NTHR) ((_Float16*)sH1[1])[idx] = (_Float16)0.0f;
    for (int idx = tid; idx < BT * H2S; idx += NTHR) ((_Float16*)sH2[1])[idx] = (_Float16)0.0f;

    __syncthreads();   // drains chunk-0 DMA (vmcnt) + init writes

    float cs0 = 0.0f, cs1 = 0.0f, cs2 = 0.0f;

    for (int i = 0; i <= Tt; ++i) {
        const int cur = i & 1, nxt = cur ^ 1;
        const int t16 = i & (CH - 1), cbuf = (i >> 4) & 1;

        // h1(i-1) fragments (used by both L1(i) and L2(i-1))
        half8 a0 = *(const half8*)&sH1[nxt][row8][q * 8];
        half8 a1 = *(const half8*)&sH1[nxt][row8][32 + q * 8];

        if (i < Tt) {   // ---- L1 step i ----
            f32x4 lo = *(const f32x4*)&sXC[cbuf][t16][2 * q][row8][0];
            f32x4 hi = *(const f32x4*)&sXC[cbuf][t16][2 * q + 1][row8][0];
            union { half8 v; fp16x2 h[4]; } axu;
            axu.h[0] = __builtin_amdgcn_cvt_pkrtz(lo[0], lo[1]);
            axu.h[1] = __builtin_amdgcn_cvt_pkrtz(lo[2], lo[3]);
            axu.h[2] = __builtin_amdgcn_cvt_pkrtz(hi[0], hi[1]);
            axu.h[3] = __builtin_amdgcn_cvt_pkrtz(hi[2], hi[3]);

            f32x4 acc[4];
            #pragma unroll
            for (int G = 0; G < 4; ++G) {
                f32x4 a = {bias1[G], bias1[G], bias1[G], bias1[G]};
                a = MFMA16(a0, w1[G][0], a);
                a = MFMA16(a1, w1[G][1], a);
                a = MFMA16(axu.v, w1[G][2], a);
                acc[G] = a;
            }
            float h0  = lstm_unit(acc[0][r0], acc[1][r0], acc[2][r0], acc[3][r0], cs0);
            float h1v = lstm_unit(acc[0][r1], acc[1][r1], acc[2][r1], acc[3][r1], cs1);
            sH1[cur][bLo][colL1]     = (_Float16)h0;
            sH1[cur][bLo + 1][colL1] = (_Float16)h1v;
        }
        if (i >= 1) {   // ---- L2 step i-1 (duplicated across wave pair) ----
            half8 ah = *(const half8*)&sH2[cur][row8][q * 8];
            f32x4 acc[4];
            #pragma unroll
            for (int G = 0; G < 4; ++G) {
                f32x4 a = {bias2[G], bias2[G], bias2[G], bias2[G]};
                a = MFMA16(ah, w2[G][0], a);
                a = MFMA16(a0, w2[G][1], a);
                a = MFMA16(a1, w2[G][2], a);
                acc[G] = a;
            }
            float h2v = lstm_unit(acc[0][rL2], acc[1][rL2], acc[2][rL2], acc[3][rL2], cs2);
            sH2[nxt][bL2][hL2] = (_Float16)h2v;
            if (i == Tt) sHead[bL2][hL2] = h2v;
        }

        // ---- chunk-boundary DMA: stage chunk (i/CH + 1) into the other buffer ----
        if ((i & (CH - 1)) == 0 && i + CH < Tt) {
            const float* gb = gbase + (size_t)(i + CH) * Ff;
            #pragma unroll
            for (int j = 0; j < 4; ++j) {
                int t = (wid << 2) | j;
                dma16(gb + (size_t)t * Ff, &sXC[cbuf ^ 1][t][0][0][0]);
            }
        }
        __syncthreads();   // single barrier per step (vmcnt drain only on boundary steps)
    }

    // ---- head ----
    if (tid < BT * NTAPS) {
        int b = tid / NTAPS, n = tid - b * NTAPS;
        float s = bhead[n];
        #pragma unroll
        for (int k = 0; k < H2; ++k) s = fmaf(sHead[b][k], Whead[n * H2 + k], s);
        out[(size_t)(b0 + b) * NTAPS + n] = s;
    }
}

extern "C" void kernel_launch(void* const* d_in, const int* in_sizes, int n_in,
                              void* d_out, int out_size, void* d_ws, size_t ws_size,
                              hipStream_t stream) {
    const float* xp    = (const float*)d_in[0];
    const float* Wih1  = (const float*)d_in[1];
    const float* Whh1  = (const float*)d_in[2];
    const float* bih1  = (const float*)d_in[3];
    const float* bhh1  = (const float*)d_in[4];
    const float* Wih2  = (const float*)d_in[5];
    const float* Whh2  = (const float*)d_in[6];
    const float* bih2  = (const float*)d_in[7];
    const float* bhh2  = (const float*)d_in[8];
    const float* Whead = (const float*)d_in[9];
    const float* bhead = (const float*)d_in[10];
    float* outp = (float*)d_out;

    hipLaunchKernelGGL(lstm2_fused, dim3(Bsz / BT), dim3(NTHR), 0, stream,
                       xp, Wih1, Whh1, bih1, bhh1, Wih2, Whh2, bih2, bhh2,
                       Whead, bhead, outp);
}